// Round 5
// baseline (380.522 us; speedup 1.0000x reference)
//
#include <hip/hip_runtime.h>
#include <hip/hip_bf16.h>

// MEASUREMENT ROUND: gemm1 K-loop amplified x32 (acc accumulates, epilogue
// scales by 1/32), gemm2 compute+store amplified x6 (stores keep reps live).
// Outputs numerically identical (tiny extra f32 rounding, threshold 2.5e9).
// Purpose: surface both kernels above the ~113us harness fills in rocprof
// top-5 to read their true per-kernel counters. dur_us WILL regress by design.

typedef __bf16 bf16_t;
typedef __attribute__((ext_vector_type(8))) __bf16 bf16x8;
typedef __attribute__((ext_vector_type(4))) float f32x4;
typedef __attribute__((ext_vector_type(8))) int i32x8;

#define NEG_INF 1000000000000.0f
#define G1_REPS 32
#define G2_REPS 6

// ws layout (bytes)
#define WS_A8   0                  // inputs fp8 [4096][768]    : 3,145,728
#define WS_WT8  3145728            // W^T fp8 [3072][768]       : 2,359,296
#define WS_Q    5505024            // Q bf16 [8][24][512][64]   : 12,582,912
#define WS_K    18087936           // K bf16 [8][24][512][64]   : 12,582,912
#define WS_RC   30670848           // ropeC f32 [512][64]       : 131,072
#define WS_RS   30801920           // ropeS f32 [512][64]       : 131,072

__device__ __forceinline__ unsigned short f2bf_bits(float x) {
  union { float f; unsigned u; } v; v.f = x;
  unsigned r = v.u + 0x7FFFu + ((v.u >> 16) & 1u);
  return (unsigned short)(r >> 16);
}

__device__ __forceinline__ int pack4_fp8(float a, float b, float c, float d) {
  int w = __builtin_amdgcn_cvt_pk_fp8_f32(a, b, 0, false);
  w = __builtin_amdgcn_cvt_pk_fp8_f32(c, d, w, true);
  return w;
}

#define GLD16(g, l) __builtin_amdgcn_global_load_lds( \
    (const __attribute__((address_space(1))) void*)(g), \
    (__attribute__((address_space(3))) void*)(l), 16, 0, 0)

// ---------------- fused prep ----------------
__global__ void prep_kernel(const float4* __restrict__ in, int4* __restrict__ outA,
                            const float* __restrict__ W, char* __restrict__ Wt8,
                            float* __restrict__ ropeC, float* __restrict__ ropeS) {
  __shared__ float s[32][33];
  if (blockIdx.x < 768) {
    int g = blockIdx.x * 256 + threadIdx.x;
    float4 v0 = in[g * 4 + 0];
    float4 v1 = in[g * 4 + 1];
    float4 v2 = in[g * 4 + 2];
    float4 v3 = in[g * 4 + 3];
    int4 o;
    o.x = pack4_fp8(v0.x, v0.y, v0.z, v0.w);
    o.y = pack4_fp8(v1.x, v1.y, v1.z, v1.w);
    o.z = pack4_fp8(v2.x, v2.y, v2.z, v2.w);
    o.w = pack4_fp8(v3.x, v3.y, v3.z, v3.w);
    outA[g] = o;
  } else if (blockIdx.x < 3072) {
    int bid = blockIdx.x - 768;
    int n0 = (bid % 96) * 32, k0 = (bid / 96) * 32;
    int tx = threadIdx.x & 31, ty = threadIdx.x >> 5;
#pragma unroll
    for (int r = 0; r < 4; ++r) {
      int k = k0 + ty + r * 8;
      s[ty + r * 8][tx] = W[(size_t)k * 3072 + n0 + tx];
    }
    __syncthreads();
    int kx = threadIdx.x & 7, tn = threadIdx.x >> 3;
    int w = pack4_fp8(s[4 * kx + 0][tn], s[4 * kx + 1][tn],
                      s[4 * kx + 2][tn], s[4 * kx + 3][tn]);
    *(int*)(Wt8 + (size_t)(n0 + tn) * 768 + k0 + 4 * kx) = w;
  } else {
    int g = (blockIdx.x - 3072) * 256 + threadIdx.x;
    int sp = g >> 6, c = g & 63;
    float inv = exp2f((float)(c >> 1) * -0.4152410118609203f);
    float ang = (float)sp * inv;
    float sn, cs;
    sincosf(ang, &sn, &cs);
    ropeC[g] = cs;
    ropeS[g] = sn;
  }
}

// ---------------- GEMM1 (MX-fp8), K-loop x G1_REPS ----------------
__global__ __launch_bounds__(256) void gemm1_kernel(
    const char* __restrict__ A8, const char* __restrict__ Bt8,
    const float* __restrict__ bias,
    const float* __restrict__ ropeC, const float* __restrict__ ropeS,
    unsigned short* __restrict__ Qo, unsigned short* __restrict__ Ko) {
  __shared__ __align__(16) char As[2][128 * 128];
  __shared__ __align__(16) char Bs[2][128 * 128];
  const int tid = threadIdx.x;
  const int lane = tid & 63;
  const int wv = tid >> 6;
  const int wr = (wv >> 1) * 64;
  const int wc = (wv & 1) * 64;

  const int bid = blockIdx.x;
  const int swz = (bid & 7) * 96 + (bid >> 3);
  const int h = swz % 24;
  const int m0 = (swz / 24) * 128;
  const int n0 = h * 128;

  f32x4 acc[4][4];
#pragma unroll
  for (int i = 0; i < 4; ++i)
#pragma unroll
    for (int j = 0; j < 4; ++j) acc[i][j] = (f32x4){0.f, 0.f, 0.f, 0.f};

  const char* pA[4];
  const char* pB[4];
#pragma unroll
  for (int i = 0; i < 4; ++i) {
    int c = 4 * wv + i;
    int row = c * 8 + (lane >> 3);
    int srcslot = (lane & 7) ^ (row & 7);
    pA[i] = A8 + (size_t)(m0 + row) * 768 + srcslot * 16;
    pB[i] = Bt8 + (size_t)(n0 + row) * 768 + srcslot * 16;
  }

#define STAGE1(buf, k0) do { \
    _Pragma("unroll") \
    for (int i = 0; i < 4; ++i) { \
      GLD16(pA[i] + (k0), As[buf] + (4 * wv + i) * 1024); \
      GLD16(pB[i] + (k0), Bs[buf] + (4 * wv + i) * 1024); \
    } \
  } while (0)

#define COMPUTE1(buf) do { \
    const int t = lane >> 4; \
    i32x8 af[4], bfr[4]; \
    _Pragma("unroll") \
    for (int m16 = 0; m16 < 4; ++m16) { \
      int row = wr + m16 * 16 + (lane & 15); \
      int x = row & 7; \
      const char* rb = As[buf] + row * 128; \
      int4 lo = *(const int4*)(rb + ((2 * t) ^ x) * 16); \
      int4 hi = *(const int4*)(rb + ((2 * t + 1) ^ x) * 16); \
      af[m16] = (i32x8){lo.x, lo.y, lo.z, lo.w, hi.x, hi.y, hi.z, hi.w}; \
    } \
    _Pragma("unroll") \
    for (int n16 = 0; n16 < 4; ++n16) { \
      int row = wc + n16 * 16 + (lane & 15); \
      int x = row & 7; \
      const char* rb = Bs[buf] + row * 128; \
      int4 lo = *(const int4*)(rb + ((2 * t) ^ x) * 16); \
      int4 hi = *(const int4*)(rb + ((2 * t + 1) ^ x) * 16); \
      bfr[n16] = (i32x8){lo.x, lo.y, lo.z, lo.w, hi.x, hi.y, hi.z, hi.w}; \
    } \
    _Pragma("unroll") \
    for (int m16 = 0; m16 < 4; ++m16) \
      _Pragma("unroll") \
      for (int n16 = 0; n16 < 4; ++n16) \
        acc[m16][n16] = __builtin_amdgcn_mfma_scale_f32_16x16x128_f8f6f4( \
            bfr[n16], af[m16], acc[m16][n16], 0, 0, \
            0, 0x7F7F7F7F, 0, 0x7F7F7F7F); \
  } while (0)

  // AMPLIFIED: accumulate the identical GEMM G1_REPS times; scale 1/G1_REPS later.
#pragma unroll 1
  for (int rep = 0; rep < G1_REPS; ++rep) {
    STAGE1(0, 0);
    __syncthreads();
#pragma unroll
    for (int kt = 0; kt < 5; ++kt) {
      const int cur = kt & 1;
      STAGE1(cur ^ 1, (kt + 1) * 128);
      COMPUTE1(cur);
      __syncthreads();
    }
    COMPUTE1(1);
    __syncthreads();   // protect buf0 before next rep's prologue stage
  }

  const float rscale = 1.0f / (float)G1_REPS;
#pragma unroll
  for (int n16 = 0; n16 < 4; ++n16) {
    int cbase = wc + n16 * 16 + ((lane >> 4) * 4);
    bool isq = (cbase < 64);
    int d = cbase & 63;
    float4 bv = *(const float4*)&bias[h * 128 + cbase];
#pragma unroll
    for (int m16 = 0; m16 < 4; ++m16) {
      int sg = m0 + wr + m16 * 16 + (lane & 15);
      int sl = sg & 511, b = sg >> 9;
      f32x4 v = acc[m16][n16];
      float q0 = v[0] * rscale + bv.x, q1 = v[1] * rscale + bv.y;
      float q2 = v[2] * rscale + bv.z, q3 = v[3] * rscale + bv.w;
      float r0 = q0, r1 = q1, r2 = q2, r3 = q3;
      if (isq) {
        float4 C = *(const float4*)&ropeC[sl * 64 + d];
        float4 S = *(const float4*)&ropeS[sl * 64 + d];
        r0 = q0 * C.x - q1 * S.x;
        r1 = q1 * C.y + q0 * S.y;
        r2 = q2 * C.z - q3 * S.z;
        r3 = q3 * C.w + q2 * S.w;
      }
      ushort4 o;
      o.x = f2bf_bits(r0); o.y = f2bf_bits(r1);
      o.z = f2bf_bits(r2); o.w = f2bf_bits(r3);
      size_t off = (((size_t)(b * 24 + h) * 512) + sl) * 64 + d;
      *(ushort4*)((isq ? Qo : Ko) + off) = o;
    }
  }
#undef STAGE1
#undef COMPUTE1
}

// ---------------- GEMM2, compute+store x G2_REPS ----------------
__global__ __launch_bounds__(256) void gemm2_kernel(
    const bf16_t* __restrict__ Q, const bf16_t* __restrict__ K,
    const float* __restrict__ mask, float* __restrict__ out) {
  __shared__ __align__(16) bf16_t Qs[128 * 64];
  __shared__ __align__(16) bf16_t Ks[128 * 64];
  const int tid = threadIdx.x;
  const int lane = tid & 63;
  const int wv = tid >> 6;
  const int wr = (wv >> 1) * 64;
  const int wc = (wv & 1) * 64;
  const int bh = blockIdx.z;
  const int b = bh / 24;
  const int m0 = blockIdx.y * 128;
  const int n0 = blockIdx.x * 128;
  const size_t base = (size_t)bh * 512 * 64;

  const int srow = lane >> 3;
  const int sslot = lane & 7;
#pragma unroll
  for (int i = 0; i < 4; ++i) {
    int c = 4 * wv + i;
    int row = 8 * c + srow;
    int fslot = sslot ^ (row & 7);
    const bf16_t* gq = Q + base + (size_t)(m0 + row) * 64 + fslot * 8;
    const bf16_t* gk = K + base + (size_t)(n0 + row) * 64 + fslot * 8;
    GLD16(gq, Qs + c * 512);
    GLD16(gk, Ks + c * 512);
  }
  __syncthreads();

  const float* mb = mask + (size_t)b * 512;
  float* ob = out + (size_t)bh * 512 * 512;

#pragma unroll 1
  for (int rep = 0; rep < G2_REPS; ++rep) {
    f32x4 acc[4][4];
#pragma unroll
    for (int i = 0; i < 4; ++i)
#pragma unroll
      for (int j = 0; j < 4; ++j) acc[i][j] = (f32x4){0.f, 0.f, 0.f, 0.f};

#pragma unroll
    for (int kk = 0; kk < 2; ++kk) {
      const int kslot = (lane >> 4) + kk * 4;
      bf16x8 af[4], bfr[4];
#pragma unroll
      for (int m16 = 0; m16 < 4; ++m16) {
        int arow = wr + m16 * 16 + (lane & 15);
        int sl = kslot ^ (arow & 7);
        af[m16] = *(const bf16x8*)(Qs + arow * 64 + sl * 8);
      }
#pragma unroll
      for (int n16 = 0; n16 < 4; ++n16) {
        int brow = wc + n16 * 16 + (lane & 15);
        int sl = kslot ^ (brow & 7);
        bfr[n16] = *(const bf16x8*)(Ks + brow * 64 + sl * 8);
      }
#pragma unroll
      for (int m16 = 0; m16 < 4; ++m16)
#pragma unroll
        for (int n16 = 0; n16 < 4; ++n16)
          acc[m16][n16] = __builtin_amdgcn_mfma_f32_16x16x32_bf16(
              bfr[n16], af[m16], acc[m16][n16], 0, 0, 0);
    }

#pragma unroll
    for (int m16 = 0; m16 < 4; ++m16) {
      int mg = m0 + wr + m16 * 16 + (lane & 15);
      float mrv = mb[mg];
      float rbias = -NEG_INF * (1.0f - mrv);
#pragma unroll
      for (int n16 = 0; n16 < 4; ++n16) {
        int nb = n0 + wc + n16 * 16 + ((lane >> 4) * 4);
        float4 mc4 = *(const float4*)&mb[nb];
        f32x4 v = acc[m16][n16];
        float4 st;
        float x0 = v[0] * mrv + rbias;
        float x1 = v[1] * mrv + rbias;
        float x2 = v[2] * mrv + rbias;
        float x3 = v[3] * mrv + rbias;
        x0 = x0 * mc4.x - NEG_INF * (1.0f - mc4.x);
        x1 = x1 * mc4.y - NEG_INF * (1.0f - mc4.y);
        x2 = x2 * mc4.z - NEG_INF * (1.0f - mc4.z);
        x3 = x3 * mc4.w - NEG_INF * (1.0f - mc4.w);
        if (mg > nb + 0) x0 -= NEG_INF;
        if (mg > nb + 1) x1 -= NEG_INF;
        if (mg > nb + 2) x2 -= NEG_INF;
        if (mg > nb + 3) x3 -= NEG_INF;
        st.x = x0 * 0.125f; st.y = x1 * 0.125f;
        st.z = x2 * 0.125f; st.w = x3 * 0.125f;
        *(float4*)(ob + (size_t)mg * 512 + nb) = st;
      }
    }
  }
}

extern "C" void kernel_launch(void* const* d_in, const int* in_sizes, int n_in,
                              void* d_out, int out_size, void* d_ws, size_t ws_size,
                              hipStream_t stream) {
  const float* inputs = (const float*)d_in[0];
  const float* mask = (const float*)d_in[1];
  const float* W = (const float*)d_in[2];
  const float* bias = (const float*)d_in[3];
  float* out = (float*)d_out;
  char* ws = (char*)d_ws;

  char* A8 = ws + WS_A8;
  char* Wt8 = ws + WS_WT8;
  unsigned short* Qb = (unsigned short*)(ws + WS_Q);
  unsigned short* Kb = (unsigned short*)(ws + WS_K);
  float* ropeC = (float*)(ws + WS_RC);
  float* ropeS = (float*)(ws + WS_RS);

  prep_kernel<<<3200, 256, 0, stream>>>((const float4*)inputs, (int4*)A8, W, Wt8,
                                        ropeC, ropeS);
  gemm1_kernel<<<768, 256, 0, stream>>>(A8, Wt8, bias, ropeC, ropeS, Qb, Kb);
  gemm2_kernel<<<dim3(4, 4, 192), 256, 0, stream>>>((const bf16_t*)Qb,
                                                    (const bf16_t*)Kb, mask, out);
}

// Round 6
// 90.992 us; speedup vs baseline: 4.1820x; 4.1820x over previous
//
#include <hip/hip_runtime.h>
#include <hip/hip_bf16.h>

// GlobalPointer logits: x = inputs@W+b -> split q/k per head -> RoPE(q) ->
// logits[b,h,m,n] = <q[b,m,h,:], k[b,n,h,:]> with mask+causal, /8.
// B=8 S=512 DIM=768 H=24 D=64. Output [8][24][512][512] f32.
// GEMM1 in MX-fp8 (e4m3, scale=1.0), swapped-operand MFMA.
// GEMM2: one block per (b,h), 512 thr, Q/K staged once in 128KB LDS,
// streaming float4 epilogue (write-BW-bound by design).

typedef __bf16 bf16_t;
typedef __attribute__((ext_vector_type(8))) __bf16 bf16x8;
typedef __attribute__((ext_vector_type(4))) float f32x4;
typedef __attribute__((ext_vector_type(8))) int i32x8;

#define NEG_INF 1000000000000.0f

// ws layout (bytes)
#define WS_A8   0                  // inputs fp8 [4096][768]    : 3,145,728
#define WS_WT8  3145728            // W^T fp8 [3072][768]       : 2,359,296
#define WS_Q    5505024            // Q bf16 [8][24][512][64]   : 12,582,912
#define WS_K    18087936           // K bf16 [8][24][512][64]   : 12,582,912
#define WS_RC   30670848           // ropeC f32 [512][64]       : 131,072
#define WS_RS   30801920           // ropeS f32 [512][64]       : 131,072

__device__ __forceinline__ unsigned short f2bf_bits(float x) {
  union { float f; unsigned u; } v; v.f = x;
  unsigned r = v.u + 0x7FFFu + ((v.u >> 16) & 1u);
  return (unsigned short)(r >> 16);
}

__device__ __forceinline__ int pack4_fp8(float a, float b, float c, float d) {
  int w = __builtin_amdgcn_cvt_pk_fp8_f32(a, b, 0, false);
  w = __builtin_amdgcn_cvt_pk_fp8_f32(c, d, w, true);
  return w;
}

#define GLD16(g, l) __builtin_amdgcn_global_load_lds( \
    (const __attribute__((address_space(1))) void*)(g), \
    (__attribute__((address_space(3))) void*)(l), 16, 0, 0)

// ---------------- fused prep ----------------
__global__ void prep_kernel(const float4* __restrict__ in, int4* __restrict__ outA,
                            const float* __restrict__ W, char* __restrict__ Wt8,
                            float* __restrict__ ropeC, float* __restrict__ ropeS) {
  __shared__ float s[32][33];
  if (blockIdx.x < 768) {
    int g = blockIdx.x * 256 + threadIdx.x;
    float4 v0 = in[g * 4 + 0];
    float4 v1 = in[g * 4 + 1];
    float4 v2 = in[g * 4 + 2];
    float4 v3 = in[g * 4 + 3];
    int4 o;
    o.x = pack4_fp8(v0.x, v0.y, v0.z, v0.w);
    o.y = pack4_fp8(v1.x, v1.y, v1.z, v1.w);
    o.z = pack4_fp8(v2.x, v2.y, v2.z, v2.w);
    o.w = pack4_fp8(v3.x, v3.y, v3.z, v3.w);
    outA[g] = o;
  } else if (blockIdx.x < 3072) {
    int bid = blockIdx.x - 768;
    int n0 = (bid % 96) * 32, k0 = (bid / 96) * 32;
    int tx = threadIdx.x & 31, ty = threadIdx.x >> 5;
#pragma unroll
    for (int r = 0; r < 4; ++r) {
      int k = k0 + ty + r * 8;
      s[ty + r * 8][tx] = W[(size_t)k * 3072 + n0 + tx];
    }
    __syncthreads();
    int kx = threadIdx.x & 7, tn = threadIdx.x >> 3;
    int w = pack4_fp8(s[4 * kx + 0][tn], s[4 * kx + 1][tn],
                      s[4 * kx + 2][tn], s[4 * kx + 3][tn]);
    *(int*)(Wt8 + (size_t)(n0 + tn) * 768 + k0 + 4 * kx) = w;
  } else {
    int g = (blockIdx.x - 3072) * 256 + threadIdx.x;
    int sp = g >> 6, c = g & 63;
    float inv = exp2f((float)(c >> 1) * -0.4152410118609203f);
    float ang = (float)sp * inv;
    float sn, cs;
    sincosf(ang, &sn, &cs);
    ropeC[g] = cs;
    ropeS[g] = sn;
  }
}

// ---------------- GEMM1 (MX-fp8): X = A*Wt^T + b, RoPE(q), split ----------------
__global__ __launch_bounds__(256) void gemm1_kernel(
    const char* __restrict__ A8, const char* __restrict__ Bt8,
    const float* __restrict__ bias,
    const float* __restrict__ ropeC, const float* __restrict__ ropeS,
    unsigned short* __restrict__ Qo, unsigned short* __restrict__ Ko) {
  __shared__ __align__(16) char As[2][128 * 128];
  __shared__ __align__(16) char Bs[2][128 * 128];
  const int tid = threadIdx.x;
  const int lane = tid & 63;
  const int wv = tid >> 6;
  const int wr = (wv >> 1) * 64;
  const int wc = (wv & 1) * 64;

  const int bid = blockIdx.x;
  const int swz = (bid & 7) * 96 + (bid >> 3);
  const int h = swz % 24;
  const int m0 = (swz / 24) * 128;
  const int n0 = h * 128;

  f32x4 acc[4][4];
#pragma unroll
  for (int i = 0; i < 4; ++i)
#pragma unroll
    for (int j = 0; j < 4; ++j) acc[i][j] = (f32x4){0.f, 0.f, 0.f, 0.f};

  const char* pA[4];
  const char* pB[4];
#pragma unroll
  for (int i = 0; i < 4; ++i) {
    int c = 4 * wv + i;
    int row = c * 8 + (lane >> 3);
    int srcslot = (lane & 7) ^ (row & 7);
    pA[i] = A8 + (size_t)(m0 + row) * 768 + srcslot * 16;
    pB[i] = Bt8 + (size_t)(n0 + row) * 768 + srcslot * 16;
  }

#define STAGE1(buf, k0) do { \
    _Pragma("unroll") \
    for (int i = 0; i < 4; ++i) { \
      GLD16(pA[i] + (k0), As[buf] + (4 * wv + i) * 1024); \
      GLD16(pB[i] + (k0), Bs[buf] + (4 * wv + i) * 1024); \
    } \
  } while (0)

#define COMPUTE1(buf) do { \
    const int t = lane >> 4; \
    i32x8 af[4], bfr[4]; \
    _Pragma("unroll") \
    for (int m16 = 0; m16 < 4; ++m16) { \
      int row = wr + m16 * 16 + (lane & 15); \
      int x = row & 7; \
      const char* rb = As[buf] + row * 128; \
      int4 lo = *(const int4*)(rb + ((2 * t) ^ x) * 16); \
      int4 hi = *(const int4*)(rb + ((2 * t + 1) ^ x) * 16); \
      af[m16] = (i32x8){lo.x, lo.y, lo.z, lo.w, hi.x, hi.y, hi.z, hi.w}; \
    } \
    _Pragma("unroll") \
    for (int n16 = 0; n16 < 4; ++n16) { \
      int row = wc + n16 * 16 + (lane & 15); \
      int x = row & 7; \
      const char* rb = Bs[buf] + row * 128; \
      int4 lo = *(const int4*)(rb + ((2 * t) ^ x) * 16); \
      int4 hi = *(const int4*)(rb + ((2 * t + 1) ^ x) * 16); \
      bfr[n16] = (i32x8){lo.x, lo.y, lo.z, lo.w, hi.x, hi.y, hi.z, hi.w}; \
    } \
    _Pragma("unroll") \
    for (int m16 = 0; m16 < 4; ++m16) \
      _Pragma("unroll") \
      for (int n16 = 0; n16 < 4; ++n16) \
        acc[m16][n16] = __builtin_amdgcn_mfma_scale_f32_16x16x128_f8f6f4( \
            bfr[n16], af[m16], acc[m16][n16], 0, 0, \
            0, 0x7F7F7F7F, 0, 0x7F7F7F7F); \
  } while (0)

  STAGE1(0, 0);
  __syncthreads();
#pragma unroll
  for (int kt = 0; kt < 5; ++kt) {
    const int cur = kt & 1;
    STAGE1(cur ^ 1, (kt + 1) * 128);
    COMPUTE1(cur);
    __syncthreads();
  }
  COMPUTE1(1);

#pragma unroll
  for (int n16 = 0; n16 < 4; ++n16) {
    int cbase = wc + n16 * 16 + ((lane >> 4) * 4);
    bool isq = (cbase < 64);
    int d = cbase & 63;
    float4 bv = *(const float4*)&bias[h * 128 + cbase];
#pragma unroll
    for (int m16 = 0; m16 < 4; ++m16) {
      int sg = m0 + wr + m16 * 16 + (lane & 15);
      int sl = sg & 511, b = sg >> 9;
      f32x4 v = acc[m16][n16];
      float q0 = v[0] + bv.x, q1 = v[1] + bv.y, q2 = v[2] + bv.z, q3 = v[3] + bv.w;
      float r0 = q0, r1 = q1, r2 = q2, r3 = q3;
      if (isq) {
        float4 C = *(const float4*)&ropeC[sl * 64 + d];
        float4 S = *(const float4*)&ropeS[sl * 64 + d];
        r0 = q0 * C.x - q1 * S.x;
        r1 = q1 * C.y + q0 * S.y;
        r2 = q2 * C.z - q3 * S.z;
        r3 = q3 * C.w + q2 * S.w;
      }
      ushort4 o;
      o.x = f2bf_bits(r0); o.y = f2bf_bits(r1);
      o.z = f2bf_bits(r2); o.w = f2bf_bits(r3);
      size_t off = (((size_t)(b * 24 + h) * 512) + sl) * 64 + d;
      *(ushort4*)((isq ? Qo : Ko) + off) = o;
    }
  }
#undef STAGE1
#undef COMPUTE1
}

// ---------------- GEMM2 v2: one block per (b,h), 512 thr, full 512x512 out ----------------
// Q,K staged once into 128KB LDS (XOR-swizzled rows: slot ^= row&7).
// Wave w owns rows [64w,64w+64). Q-frags hoisted to regs; 8 column chunks of
// {8 ds_read + 32 MFMA + mask/causal + 16 float4 stores} -> streaming writes.
__global__ __launch_bounds__(512) void gemm2_kernel(
    const bf16_t* __restrict__ Q, const bf16_t* __restrict__ K,
    const float* __restrict__ mask, float* __restrict__ out) {
  __shared__ __align__(16) bf16_t Qs[512 * 64];
  __shared__ __align__(16) bf16_t Ks[512 * 64];
  const int tid = threadIdx.x;
  const int lane = tid & 63;
  const int wv = tid >> 6;          // 0..7
  const int bh = blockIdx.x;
  const int b = bh / 24;
  const size_t base = (size_t)bh * 512 * 64;

  // stage Q,K: 512 rows x 128B each; thread t -> rows i*64 + (t>>3), slot t&7
#pragma unroll
  for (int i = 0; i < 8; ++i) {
    int row = i * 64 + (tid >> 3);
    int slot = tid & 7;
    int srcslot = slot ^ (row & 7);
    GLD16(Q + base + (size_t)row * 64 + srcslot * 8, Qs + row * 64 + slot * 8);
    GLD16(K + base + (size_t)row * 64 + srcslot * 8, Ks + row * 64 + slot * 8);
  }
  __syncthreads();

  // hoist Q fragments: af[m16][kk] for this wave's 64 rows
  bf16x8 af[4][2];
#pragma unroll
  for (int m16 = 0; m16 < 4; ++m16) {
    int row = wv * 64 + m16 * 16 + (lane & 15);
    int x = row & 7;
#pragma unroll
    for (int kk = 0; kk < 2; ++kk) {
      int sl = ((lane >> 4) + kk * 4) ^ x;
      af[m16][kk] = *(const bf16x8*)(Qs + row * 64 + sl * 8);
    }
  }

  const float* mb = mask + (size_t)b * 512;
  float* ob = out + (size_t)bh * 512 * 512;

  // row-mask factors for this wave's 4 m16 tiles
  float mrv[4], rbias[4];
#pragma unroll
  for (int m16 = 0; m16 < 4; ++m16) {
    mrv[m16] = mb[wv * 64 + m16 * 16 + (lane & 15)];
    rbias[m16] = -NEG_INF * (1.0f - mrv[m16]);
  }

#pragma unroll 1
  for (int nc = 0; nc < 8; ++nc) {      // 8 column chunks of 64
    f32x4 acc[4][4];
#pragma unroll
    for (int i = 0; i < 4; ++i)
#pragma unroll
      for (int j = 0; j < 4; ++j) acc[i][j] = (f32x4){0.f, 0.f, 0.f, 0.f};

    bf16x8 bfr[4][2];
#pragma unroll
    for (int n16 = 0; n16 < 4; ++n16) {
      int row = nc * 64 + n16 * 16 + (lane & 15);
      int x = row & 7;
#pragma unroll
      for (int kk = 0; kk < 2; ++kk) {
        int sl = ((lane >> 4) + kk * 4) ^ x;
        bfr[n16][kk] = *(const bf16x8*)(Ks + row * 64 + sl * 8);
      }
    }
#pragma unroll
    for (int kk = 0; kk < 2; ++kk)
#pragma unroll
      for (int m16 = 0; m16 < 4; ++m16)
#pragma unroll
        for (int n16 = 0; n16 < 4; ++n16)
          acc[m16][n16] = __builtin_amdgcn_mfma_f32_16x16x32_bf16(
              bfr[n16][kk], af[m16][kk], acc[m16][n16], 0, 0, 0);

#pragma unroll
    for (int m16 = 0; m16 < 4; ++m16) {
      int mg = wv * 64 + m16 * 16 + (lane & 15);
#pragma unroll
      for (int n16 = 0; n16 < 4; ++n16) {
        int nb = nc * 64 + n16 * 16 + ((lane >> 4) * 4);
        float4 mc4 = *(const float4*)&mb[nb];
        f32x4 v = acc[m16][n16];
        float x0 = v[0] * mrv[m16] + rbias[m16];
        float x1 = v[1] * mrv[m16] + rbias[m16];
        float x2 = v[2] * mrv[m16] + rbias[m16];
        float x3 = v[3] * mrv[m16] + rbias[m16];
        x0 = x0 * mc4.x - NEG_INF * (1.0f - mc4.x);
        x1 = x1 * mc4.y - NEG_INF * (1.0f - mc4.y);
        x2 = x2 * mc4.z - NEG_INF * (1.0f - mc4.z);
        x3 = x3 * mc4.w - NEG_INF * (1.0f - mc4.w);
        if (mg > nb + 0) x0 -= NEG_INF;
        if (mg > nb + 1) x1 -= NEG_INF;
        if (mg > nb + 2) x2 -= NEG_INF;
        if (mg > nb + 3) x3 -= NEG_INF;
        float4 st;
        st.x = x0 * 0.125f; st.y = x1 * 0.125f;
        st.z = x2 * 0.125f; st.w = x3 * 0.125f;
        *(float4*)(ob + (size_t)mg * 512 + nb) = st;
      }
    }
  }
}

extern "C" void kernel_launch(void* const* d_in, const int* in_sizes, int n_in,
                              void* d_out, int out_size, void* d_ws, size_t ws_size,
                              hipStream_t stream) {
  const float* inputs = (const float*)d_in[0];
  const float* mask = (const float*)d_in[1];
  const float* W = (const float*)d_in[2];
  const float* bias = (const float*)d_in[3];
  float* out = (float*)d_out;
  char* ws = (char*)d_ws;

  char* A8 = ws + WS_A8;
  char* Wt8 = ws + WS_WT8;
  unsigned short* Qb = (unsigned short*)(ws + WS_Q);
  unsigned short* Kb = (unsigned short*)(ws + WS_K);
  float* ropeC = (float*)(ws + WS_RC);
  float* ropeS = (float*)(ws + WS_RS);

  prep_kernel<<<3200, 256, 0, stream>>>((const float4*)inputs, (int4*)A8, W, Wt8,
                                        ropeC, ropeS);
  gemm1_kernel<<<768, 256, 0, stream>>>(A8, Wt8, bias, ropeC, ropeS, Qb, Kb);
  gemm2_kernel<<<192, 512, 0, stream>>>((const bf16_t*)Qb, (const bf16_t*)Kb,
                                        mask, out);
}

// Round 7
// 78.567 us; speedup vs baseline: 4.8433x; 1.1581x over previous
//
#include <hip/hip_runtime.h>
#include <hip/hip_bf16.h>

// GlobalPointer logits: x = inputs@W+b -> split q/k per head -> RoPE(q) ->
// logits[b,h,m,n] = <q[b,m,h,:], k[b,n,h,:]> with mask+causal, /8.
// B=8 S=512 DIM=768 H=24 D=64. Output [8][24][512][512] f32.
// GEMM1 in MX-fp8 (e4m3, scale=1.0), swapped-operand MFMA.
// GEMM2 v3: 768 blocks x 256 thr, one 256x256 quadrant per block,
// 64KB LDS (2 blocks/CU), XCD-swizzled so a head's 4 quadrants share L2,
// lean epilogue with tile-uniform causal classes.

typedef __bf16 bf16_t;
typedef __attribute__((ext_vector_type(8))) __bf16 bf16x8;
typedef __attribute__((ext_vector_type(4))) float f32x4;
typedef __attribute__((ext_vector_type(8))) int i32x8;

#define NEG_INF 1000000000000.0f
#define K1_8TH  125000000000.0f   // NEG_INF/8

// ws layout (bytes)
#define WS_A8   0                  // inputs fp8 [4096][768]    : 3,145,728
#define WS_WT8  3145728            // W^T fp8 [3072][768]       : 2,359,296
#define WS_Q    5505024            // Q bf16 [8][24][512][64]   : 12,582,912
#define WS_K    18087936           // K bf16 [8][24][512][64]   : 12,582,912
#define WS_RC   30670848           // ropeC f32 [512][64]       : 131,072
#define WS_RS   30801920           // ropeS f32 [512][64]       : 131,072

__device__ __forceinline__ unsigned short f2bf_bits(float x) {
  union { float f; unsigned u; } v; v.f = x;
  unsigned r = v.u + 0x7FFFu + ((v.u >> 16) & 1u);
  return (unsigned short)(r >> 16);
}

__device__ __forceinline__ int pack4_fp8(float a, float b, float c, float d) {
  int w = __builtin_amdgcn_cvt_pk_fp8_f32(a, b, 0, false);
  w = __builtin_amdgcn_cvt_pk_fp8_f32(c, d, w, true);
  return w;
}

#define GLD16(g, l) __builtin_amdgcn_global_load_lds( \
    (const __attribute__((address_space(1))) void*)(g), \
    (__attribute__((address_space(3))) void*)(l), 16, 0, 0)

// ---------------- fused prep ----------------
__global__ void prep_kernel(const float4* __restrict__ in, int4* __restrict__ outA,
                            const float* __restrict__ W, char* __restrict__ Wt8,
                            float* __restrict__ ropeC, float* __restrict__ ropeS) {
  __shared__ float s[32][33];
  if (blockIdx.x < 768) {
    int g = blockIdx.x * 256 + threadIdx.x;
    float4 v0 = in[g * 4 + 0];
    float4 v1 = in[g * 4 + 1];
    float4 v2 = in[g * 4 + 2];
    float4 v3 = in[g * 4 + 3];
    int4 o;
    o.x = pack4_fp8(v0.x, v0.y, v0.z, v0.w);
    o.y = pack4_fp8(v1.x, v1.y, v1.z, v1.w);
    o.z = pack4_fp8(v2.x, v2.y, v2.z, v2.w);
    o.w = pack4_fp8(v3.x, v3.y, v3.z, v3.w);
    outA[g] = o;
  } else if (blockIdx.x < 3072) {
    int bid = blockIdx.x - 768;
    int n0 = (bid % 96) * 32, k0 = (bid / 96) * 32;
    int tx = threadIdx.x & 31, ty = threadIdx.x >> 5;
#pragma unroll
    for (int r = 0; r < 4; ++r) {
      int k = k0 + ty + r * 8;
      s[ty + r * 8][tx] = W[(size_t)k * 3072 + n0 + tx];
    }
    __syncthreads();
    int kx = threadIdx.x & 7, tn = threadIdx.x >> 3;
    int w = pack4_fp8(s[4 * kx + 0][tn], s[4 * kx + 1][tn],
                      s[4 * kx + 2][tn], s[4 * kx + 3][tn]);
    *(int*)(Wt8 + (size_t)(n0 + tn) * 768 + k0 + 4 * kx) = w;
  } else {
    int g = (blockIdx.x - 3072) * 256 + threadIdx.x;
    int sp = g >> 6, c = g & 63;
    float inv = exp2f((float)(c >> 1) * -0.4152410118609203f);
    float ang = (float)sp * inv;
    float sn, cs;
    sincosf(ang, &sn, &cs);
    ropeC[g] = cs;
    ropeS[g] = sn;
  }
}

// ---------------- GEMM1 (MX-fp8): X = A*Wt^T + b, RoPE(q), split ----------------
__global__ __launch_bounds__(256) void gemm1_kernel(
    const char* __restrict__ A8, const char* __restrict__ Bt8,
    const float* __restrict__ bias,
    const float* __restrict__ ropeC, const float* __restrict__ ropeS,
    unsigned short* __restrict__ Qo, unsigned short* __restrict__ Ko) {
  __shared__ __align__(16) char As[2][128 * 128];
  __shared__ __align__(16) char Bs[2][128 * 128];
  const int tid = threadIdx.x;
  const int lane = tid & 63;
  const int wv = tid >> 6;
  const int wr = (wv >> 1) * 64;
  const int wc = (wv & 1) * 64;

  const int bid = blockIdx.x;
  const int swz = (bid & 7) * 96 + (bid >> 3);
  const int h = swz % 24;
  const int m0 = (swz / 24) * 128;
  const int n0 = h * 128;

  f32x4 acc[4][4];
#pragma unroll
  for (int i = 0; i < 4; ++i)
#pragma unroll
    for (int j = 0; j < 4; ++j) acc[i][j] = (f32x4){0.f, 0.f, 0.f, 0.f};

  const char* pA[4];
  const char* pB[4];
#pragma unroll
  for (int i = 0; i < 4; ++i) {
    int c = 4 * wv + i;
    int row = c * 8 + (lane >> 3);
    int srcslot = (lane & 7) ^ (row & 7);
    pA[i] = A8 + (size_t)(m0 + row) * 768 + srcslot * 16;
    pB[i] = Bt8 + (size_t)(n0 + row) * 768 + srcslot * 16;
  }

#define STAGE1(buf, k0) do { \
    _Pragma("unroll") \
    for (int i = 0; i < 4; ++i) { \
      GLD16(pA[i] + (k0), As[buf] + (4 * wv + i) * 1024); \
      GLD16(pB[i] + (k0), Bs[buf] + (4 * wv + i) * 1024); \
    } \
  } while (0)

#define COMPUTE1(buf) do { \
    const int t = lane >> 4; \
    i32x8 af[4], bfr[4]; \
    _Pragma("unroll") \
    for (int m16 = 0; m16 < 4; ++m16) { \
      int row = wr + m16 * 16 + (lane & 15); \
      int x = row & 7; \
      const char* rb = As[buf] + row * 128; \
      int4 lo = *(const int4*)(rb + ((2 * t) ^ x) * 16); \
      int4 hi = *(const int4*)(rb + ((2 * t + 1) ^ x) * 16); \
      af[m16] = (i32x8){lo.x, lo.y, lo.z, lo.w, hi.x, hi.y, hi.z, hi.w}; \
    } \
    _Pragma("unroll") \
    for (int n16 = 0; n16 < 4; ++n16) { \
      int row = wc + n16 * 16 + (lane & 15); \
      int x = row & 7; \
      const char* rb = Bs[buf] + row * 128; \
      int4 lo = *(const int4*)(rb + ((2 * t) ^ x) * 16); \
      int4 hi = *(const int4*)(rb + ((2 * t + 1) ^ x) * 16); \
      bfr[n16] = (i32x8){lo.x, lo.y, lo.z, lo.w, hi.x, hi.y, hi.z, hi.w}; \
    } \
    _Pragma("unroll") \
    for (int m16 = 0; m16 < 4; ++m16) \
      _Pragma("unroll") \
      for (int n16 = 0; n16 < 4; ++n16) \
        acc[m16][n16] = __builtin_amdgcn_mfma_scale_f32_16x16x128_f8f6f4( \
            bfr[n16], af[m16], acc[m16][n16], 0, 0, \
            0, 0x7F7F7F7F, 0, 0x7F7F7F7F); \
  } while (0)

  STAGE1(0, 0);
  __syncthreads();
#pragma unroll
  for (int kt = 0; kt < 5; ++kt) {
    const int cur = kt & 1;
    STAGE1(cur ^ 1, (kt + 1) * 128);
    COMPUTE1(cur);
    __syncthreads();
  }
  COMPUTE1(1);

#pragma unroll
  for (int n16 = 0; n16 < 4; ++n16) {
    int cbase = wc + n16 * 16 + ((lane >> 4) * 4);
    bool isq = (cbase < 64);
    int d = cbase & 63;
    float4 bv = *(const float4*)&bias[h * 128 + cbase];
#pragma unroll
    for (int m16 = 0; m16 < 4; ++m16) {
      int sg = m0 + wr + m16 * 16 + (lane & 15);
      int sl = sg & 511, b = sg >> 9;
      f32x4 v = acc[m16][n16];
      float q0 = v[0] + bv.x, q1 = v[1] + bv.y, q2 = v[2] + bv.z, q3 = v[3] + bv.w;
      float r0 = q0, r1 = q1, r2 = q2, r3 = q3;
      if (isq) {
        float4 C = *(const float4*)&ropeC[sl * 64 + d];
        float4 S = *(const float4*)&ropeS[sl * 64 + d];
        r0 = q0 * C.x - q1 * S.x;
        r1 = q1 * C.y + q0 * S.y;
        r2 = q2 * C.z - q3 * S.z;
        r3 = q3 * C.w + q2 * S.w;
      }
      ushort4 o;
      o.x = f2bf_bits(r0); o.y = f2bf_bits(r1);
      o.z = f2bf_bits(r2); o.w = f2bf_bits(r3);
      size_t off = (((size_t)(b * 24 + h) * 512) + sl) * 64 + d;
      *(ushort4*)((isq ? Qo : Ko) + off) = o;
    }
  }
#undef STAGE1
#undef COMPUTE1
}

// ---------------- GEMM2 v3: 768 blocks x 256 thr, 256x256 quadrant ----------------
// Block -> (bh, quad): XCD-swizzled so one head's 4 quadrants land on one XCD.
// Q rows [m0,m0+256) + K rows [n0,n0+256) staged once (64KB, XOR-swizzled).
// Wave w owns 64 rows; 4 column chunks of {8 ds_read + 32 MFMA + lean epilogue}.
// Epilogue: st = fma(v, mr*CM, ADD); CM=mc/8, ADD=fma(rb,CM,colC) - causal term;
// causal classes tile-uniform (t0 vs c0): all / none / diagonal (lane-const czk).
__global__ __launch_bounds__(256, 2) void gemm2_kernel(
    const bf16_t* __restrict__ Q, const bf16_t* __restrict__ K,
    const float* __restrict__ mask, float* __restrict__ out) {
  __shared__ __align__(16) bf16_t Qs[256 * 64];
  __shared__ __align__(16) bf16_t Ks[256 * 64];
  const int tid = threadIdx.x;
  const int lane = tid & 63;
  const int wv = tid >> 6;          // 0..3

  // 768 blocks: XCD gets 96 consecutive logical ids = 24 heads x 4 quads
  const int swz = (blockIdx.x & 7) * 96 + (blockIdx.x >> 3);
  const int bh = swz >> 2;
  const int quad = swz & 3;
  const int m0 = (quad >> 1) * 256;   // row quadrant
  const int n0 = (quad & 1) * 256;    // col quadrant
  const int b = bh / 24;
  const size_t base = (size_t)bh * 512 * 64;

  // stage Q rows m0.., K rows n0..: 256 rows x 128B each
#pragma unroll
  for (int i = 0; i < 8; ++i) {
    int row = i * 32 + (tid >> 3);
    int slot = tid & 7;
    int srcslot = slot ^ (row & 7);
    GLD16(Q + base + (size_t)(m0 + row) * 64 + srcslot * 8, Qs + row * 64 + slot * 8);
    GLD16(K + base + (size_t)(n0 + row) * 64 + srcslot * 8, Ks + row * 64 + slot * 8);
  }
  __syncthreads();

  // hoist Q fragments for this wave's 64 rows
  bf16x8 af[4][2];
#pragma unroll
  for (int m16 = 0; m16 < 4; ++m16) {
    int row = wv * 64 + m16 * 16 + (lane & 15);
    int x = row & 7;
#pragma unroll
    for (int kk = 0; kk < 2; ++kk) {
      int sl = ((lane >> 4) + kk * 4) ^ x;
      af[m16][kk] = *(const bf16x8*)(Qs + row * 64 + sl * 8);
    }
  }

  const float* mb = mask + (size_t)b * 512;
  float* ob = out + (size_t)bh * 512 * 512;

  // per-wave row-mask terms
  float mr[4], rb[4];
#pragma unroll
  for (int m16 = 0; m16 < 4; ++m16) {
    mr[m16] = mb[m0 + wv * 64 + m16 * 16 + (lane & 15)];
    rb[m16] = -NEG_INF * (1.0f - mr[m16]);
  }
  // diagonal-tile causal term (lane-constant): czk[j] = K1 if (lane&15) > (lane>>4)*4+j
  float czk[4];
#pragma unroll
  for (int j = 0; j < 4; ++j)
    czk[j] = ((lane & 15) > ((lane >> 4) * 4 + j)) ? K1_8TH : 0.0f;

#pragma unroll 1
  for (int nc = 0; nc < 4; ++nc) {      // 4 column chunks of 64
    f32x4 acc[4][4];
#pragma unroll
    for (int i = 0; i < 4; ++i)
#pragma unroll
      for (int j = 0; j < 4; ++j) acc[i][j] = (f32x4){0.f, 0.f, 0.f, 0.f};

    bf16x8 bfr[4][2];
#pragma unroll
    for (int n16 = 0; n16 < 4; ++n16) {
      int row = nc * 64 + n16 * 16 + (lane & 15);
      int x = row & 7;
#pragma unroll
      for (int kk = 0; kk < 2; ++kk) {
        int sl = ((lane >> 4) + kk * 4) ^ x;
        bfr[n16][kk] = *(const bf16x8*)(Ks + row * 64 + sl * 8);
      }
    }
#pragma unroll
    for (int kk = 0; kk < 2; ++kk)
#pragma unroll
      for (int m16 = 0; m16 < 4; ++m16)
#pragma unroll
        for (int n16 = 0; n16 < 4; ++n16)
          acc[m16][n16] = __builtin_amdgcn_mfma_f32_16x16x32_bf16(
              bfr[n16][kk], af[m16][kk], acc[m16][n16], 0, 0, 0);

    // per-chunk column terms: CM = mc/8, colC = K1*mc - K1
    float4 CM[4], colC[4];
#pragma unroll
    for (int n16 = 0; n16 < 4; ++n16) {
      int nb = n0 + nc * 64 + n16 * 16 + ((lane >> 4) * 4);
      float4 mc4 = *(const float4*)&mb[nb];
      CM[n16].x = mc4.x * 0.125f; CM[n16].y = mc4.y * 0.125f;
      CM[n16].z = mc4.z * 0.125f; CM[n16].w = mc4.w * 0.125f;
      colC[n16].x = K1_8TH * mc4.x - K1_8TH;
      colC[n16].y = K1_8TH * mc4.y - K1_8TH;
      colC[n16].z = K1_8TH * mc4.z - K1_8TH;
      colC[n16].w = K1_8TH * mc4.w - K1_8TH;
    }

#pragma unroll
    for (int m16 = 0; m16 < 4; ++m16) {
      int mgl = wv * 64 + m16 * 16 + (lane & 15);      // local row
      int t0 = m0 + wv * 64 + m16 * 16;                 // tile row base (global)
      float* rowp = ob + (size_t)(m0 + mgl) * 512;
#pragma unroll
      for (int n16 = 0; n16 < 4; ++n16) {
        int c0 = n0 + nc * 64 + n16 * 16;               // tile col base (global)
        int nbl = nc * 64 + n16 * 16 + ((lane >> 4) * 4);  // local col
        f32x4 v = acc[m16][n16];
        float a0 = mr[m16] * CM[n16].x, a1 = mr[m16] * CM[n16].y;
        float a2 = mr[m16] * CM[n16].z, a3 = mr[m16] * CM[n16].w;
        float d0 = rb[m16] * CM[n16].x + colC[n16].x;
        float d1 = rb[m16] * CM[n16].y + colC[n16].y;
        float d2 = rb[m16] * CM[n16].z + colC[n16].z;
        float d3 = rb[m16] * CM[n16].w + colC[n16].w;
        if (t0 > c0) {          // fully causal tile
          d0 -= K1_8TH; d1 -= K1_8TH; d2 -= K1_8TH; d3 -= K1_8TH;
        } else if (t0 == c0) {  // diagonal tile: lane-constant mask
          d0 -= czk[0]; d1 -= czk[1]; d2 -= czk[2]; d3 -= czk[3];
        }                       // t0 < c0: no causal
        float4 st;
        st.x = v[0] * a0 + d0;
        st.y = v[1] * a1 + d1;
        st.z = v[2] * a2 + d2;
        st.w = v[3] * a3 + d3;
        *(float4*)(rowp + n0 + nbl) = st;
      }
    }
  }
}

extern "C" void kernel_launch(void* const* d_in, const int* in_sizes, int n_in,
                              void* d_out, int out_size, void* d_ws, size_t ws_size,
                              hipStream_t stream) {
  const float* inputs = (const float*)d_in[0];
  const float* mask = (const float*)d_in[1];
  const float* W = (const float*)d_in[2];
  const float* bias = (const float*)d_in[3];
  float* out = (float*)d_out;
  char* ws = (char*)d_ws;

  char* A8 = ws + WS_A8;
  char* Wt8 = ws + WS_WT8;
  unsigned short* Qb = (unsigned short*)(ws + WS_Q);
  unsigned short* Kb = (unsigned short*)(ws + WS_K);
  float* ropeC = (float*)(ws + WS_RC);
  float* ropeS = (float*)(ws + WS_RS);

  prep_kernel<<<3200, 256, 0, stream>>>((const float4*)inputs, (int4*)A8, W, Wt8,
                                        ropeC, ropeS);
  gemm1_kernel<<<768, 256, 0, stream>>>(A8, Wt8, bias, ropeC, ropeS, Qb, Kb);
  gemm2_kernel<<<768, 256, 0, stream>>>((const bf16_t*)Qb, (const bf16_t*)Kb,
                                        mask, out);
}